// Round 28
// baseline (69.253 us; speedup 1.0000x reference)
//
#include <hip/hip_runtime.h>
#include <hip/hip_bf16.h>

#define H_   32
#define KVH_ 8
#define D_   128
#define DV_  128
#define SEQ_ 1024
#define QKD  (H_*D_)
#define KVD  (KVH_*D_)
#define CS_  (0.08838834764831845f * 1.4426950408889634f)  // SCALE*log2(e)
#define MFIX 8.0f   // fixed softmax max (log2 units)
#define VOFF 8388608  // Vt = Kb + 8 MB in d_ws

typedef __attribute__((ext_vector_type(8))) short bf16x8;
typedef __attribute__((ext_vector_type(8))) unsigned short u16x8;
typedef __attribute__((ext_vector_type(4))) float f32x4;
typedef __attribute__((ext_vector_type(4))) unsigned int u32x4;

typedef const __attribute__((address_space(1))) void* gp_t;
typedef __attribute__((address_space(3))) void* lp_t;

#if __has_builtin(__builtin_amdgcn_exp2f)
#define EXP2F(x) __builtin_amdgcn_exp2f(x)
#else
#define EXP2F(x) exp2f(x)
#endif

static __device__ __forceinline__ unsigned short f2b(float x) {
    __hip_bfloat16 b = __float2bfloat16(x);
    return __builtin_bit_cast(unsigned short, b);
}
static __device__ __forceinline__ unsigned pk2(float a, float b) {
    return (unsigned)f2b(a) | ((unsigned)f2b(b) << 16);
}

// ---------- fused pre-pass (unchanged from R23) ----------
// blocks [0,2048): K f32 [T][KVH*128] -> bf16 [bh][s][128]
// blocks [2048,4096): V f32 -> bf16 transposed + slot-permuted [bh][dv][slot]
//   slot c (within 32-group): k_local = 4*((c>>3)&3) + (c&3) + 16*((c>>2)&1)
__global__ __launch_bounds__(256)
void prep_kv(const float* __restrict__ K, const float* __restrict__ V,
             unsigned short* __restrict__ Kb, unsigned short* __restrict__ Vt) {
    if (blockIdx.x < 2048) {
        const int gt = blockIdx.x * 256 + threadIdx.x;
        const int q  = gt & 15;
        const int r  = gt >> 4;
        const int s  = r & 1023;
        const int bh = r >> 10;
        const int b = bh >> 3, kvh = bh & 7;
        const float* src = K + ((size_t)(b * SEQ_ + s)) * KVD + kvh * D_ + q * 8;
        float4 a = *(const float4*)src;
        float4 c = *(const float4*)(src + 4);
        u32x4 o = { pk2(a.x, a.y), pk2(a.z, a.w), pk2(c.x, c.y), pk2(c.z, c.w) };
        *(u32x4*)(Kb + (size_t)r * 128 + q * 8) = o;
    } else {
        const int gt = (blockIdx.x - 2048) * 256 + threadIdx.x;
        const int dv = gt & 127;
        const int uc = (gt >> 7) & 127;
        const int bh = gt >> 14;
        const int b = bh >> 3, kvh = bh & 7;
        const int C  = uc * 8;
        const int t  = C >> 5;
        const float* src = V + ((size_t)(b * SEQ_)) * KVD + kvh * DV_ + dv;
        unsigned short e[8];
#pragma unroll
        for (int i = 0; i < 8; ++i) {
            const int c = (C & 31) + i;
            const int kl = 4 * ((c >> 3) & 3) + (c & 3) + 16 * ((c >> 2) & 1);
            const int s = (t << 5) + kl;
            e[i] = f2b(src[(size_t)s * KVD]);
        }
        u16x8 o = { e[0], e[1], e[2], e[3], e[4], e[5], e[6], e[7] };
        *(u16x8*)(Vt + ((size_t)bh * 128 + dv) * SEQ_ + C) = o;
    }
}

// ---------- attention: 8 waves, QBLK=128, KVBLK=64, phase-batched + setprio ----------
// R27 (67.9us) + s_setprio(1) around the batched MFMA phases. T5 is
// structure-conditional: null on lockstep bodies (confirmed R26) but positive
// on phase-split schedules (m218b/m224) -- R27's batched QK/softmax/PV phases
// now meet that prerequisite (waves occupy distinct roles per instant).
// Grid 1024 unpaired, LPT (qt = 7-rank) + kvh-keyed XCD locking.
// KS tile: [64 k][128 d] bf16, 256B rows, slot-swizzle ^(row&7) (read XOR (lo&7)<<4)
// VT tile: [128 dv][64 slot] bf16, 128B rows, slot-swizzle ^(dv&7) (read XOR (lo&7)<<4)
__global__ __launch_bounds__(512)
void attn_fwd(const float* __restrict__ Q,
              const unsigned short* __restrict__ Kb,
              float* __restrict__ O) {
    __shared__ __align__(16) unsigned short KS[2][64 * 128];   // 16 KB each
    __shared__ __align__(16) unsigned short VT[2][128 * 64];   // 16 KB each

    const int raw = (int)blockIdx.x;
    const int qt  = 7 - (raw >> 7);        // LPT: longest first (8 q-tiles of 128 rows)
    const int low = raw & 127;
    const int kvh = low & 7;               // blockIdx%8 -> XCD-locked kvh
    const int hq  = (low >> 3) & 3;
    const int b   = low >> 5;
    const int h   = kvh * 4 + hq;
    const int bh  = b * 8 + kvh;

    const int tid = threadIdx.x;
    const int w   = tid >> 6;              // wave 0..7
    const int l   = tid & 63;
    const int lo  = l & 15;
    const int g   = l >> 4;

    // staging source offsets (pre-swizzled), thread stages 2 K + 2 V 16B units
    const int kr0 = tid >> 4, ks0 = tid & 15;
    const int kr1 = kr0 + 32;
    const int offk0 = kr0 * 256 + (((ks0 & 8) | ((ks0 & 7) ^ (kr0 & 7))) << 4);
    const int offk1 = kr1 * 256 + (((ks0 & 8) | ((ks0 & 7) ^ (kr1 & 7))) << 4);
    const int dv0 = tid >> 3, vi = tid & 7;
    const int offv0 = VOFF + dv0 * 2048 + ((vi ^ (dv0 & 7)) << 4);
    const int offv1 = VOFF + (dv0 + 64) * 2048 + ((vi ^ (dv0 & 7)) << 4);

    const char* base = (const char*)Kb + (size_t)bh * 262144;  // 1024*128*2

    auto issue = [&](int t, int dsel) {
        char* ksd = (char*)KS[dsel] + w * 1024;
        char* vsd = (char*)VT[dsel] + w * 1024;
        const int ko = t * 16384;   // 64 rows * 256B per chunk
        const int vo = t * 128;     // 64 slots * 2B per chunk within each dv row
        __builtin_amdgcn_global_load_lds((gp_t)(base + (size_t)(offk0 + ko)), (lp_t)ksd,          16, 0, 0);
        __builtin_amdgcn_global_load_lds((gp_t)(base + (size_t)(offk1 + ko)), (lp_t)(ksd + 8192), 16, 0, 0);
        __builtin_amdgcn_global_load_lds((gp_t)(base + (size_t)(offv0 + vo)), (lp_t)vsd,          16, 0, 0);
        __builtin_amdgcn_global_load_lds((gp_t)(base + (size_t)(offv1 + vo)), (lp_t)(vsd + 8192), 16, 0, 0);
    };

    const int ntiles = 2 * qt + 2;         // 64k chunks: cover k <= qt*128+127
    const int qw0    = qt * 128 + w * 16;
    const int jmaxw  = (qw0 + 15) >> 6;    // last chunk this wave needs

    // Q fragments pre-scaled by SCALE*log2(e): row = lo, d = 32c + 8g + e
    const float* Qb = Q + ((size_t)(b * SEQ_ + qw0 + lo)) * QKD + h * D_;
    bf16x8 qf[4];
#pragma unroll
    for (int cc = 0; cc < 4; ++cc) {
        const float* qp = Qb + cc * 32 + g * 8;
        float4 x0 = *(const float4*)(qp);
        float4 x1 = *(const float4*)(qp + 4);
        bf16x8 f;
        f[0] = f2b(x0.x * CS_); f[1] = f2b(x0.y * CS_);
        f[2] = f2b(x0.z * CS_); f[3] = f2b(x0.w * CS_);
        f[4] = f2b(x1.x * CS_); f[5] = f2b(x1.y * CS_);
        f[6] = f2b(x1.z * CS_); f[7] = f2b(x1.w * CS_);
        qf[cc] = f;
    }

    float lsum = 0.f;
    f32x4 o_[8];
#pragma unroll
    for (int db = 0; db < 8; ++db) o_[db] = (f32x4){0.f, 0.f, 0.f, 0.f};

    issue(0, 0);

#pragma unroll 1
    for (int j = 0; j < ntiles; ++j) {
        __syncthreads();                       // chunk j landed; buf[(j+1)&1] free
        if (j + 1 < ntiles) issue(j + 1, (j + 1) & 1);
        if (j <= jmaxw) {
            const int d = j & 1;
            const char* kbase = (const char*)KS[d];
            const char* vbase = (const char*)VT[d];
            const int sw = (lo & 7) << 4;
            const int q_ = qw0 + lo;

            const int k0a = j * 64;
            const int k0b = j * 64 + 32;
            const bool do1 = (k0b <= qw0 + 15);    // wave-uniform

            // ---- phase 1: QK for both sub-tiles (up to 16 back-to-back MFMA) ----
            f32x4 sa0 = (f32x4){0.f, 0.f, 0.f, 0.f};
            f32x4 sa1 = (f32x4){0.f, 0.f, 0.f, 0.f};
            f32x4 sb0 = (f32x4){0.f, 0.f, 0.f, 0.f};
            f32x4 sb1 = (f32x4){0.f, 0.f, 0.f, 0.f};
            __builtin_amdgcn_s_setprio(1);
#pragma unroll
            for (int cc = 0; cc < 4; ++cc) {
                bf16x8 kf0 = *(const bf16x8*)(kbase + (((lo) * 256 + cc * 64 + g * 16) ^ sw));
                bf16x8 kf1 = *(const bf16x8*)(kbase + (((16 + lo) * 256 + cc * 64 + g * 16) ^ sw));
                sa0 = __builtin_amdgcn_mfma_f32_16x16x32_bf16(kf0, qf[cc], sa0, 0, 0, 0);
                sa1 = __builtin_amdgcn_mfma_f32_16x16x32_bf16(kf1, qf[cc], sa1, 0, 0, 0);
            }
            if (do1) {
#pragma unroll
                for (int cc = 0; cc < 4; ++cc) {
                    bf16x8 kf0 = *(const bf16x8*)(kbase + (((32 + lo) * 256 + cc * 64 + g * 16) ^ sw));
                    bf16x8 kf1 = *(const bf16x8*)(kbase + (((48 + lo) * 256 + cc * 64 + g * 16) ^ sw));
                    sb0 = __builtin_amdgcn_mfma_f32_16x16x32_bf16(kf0, qf[cc], sb0, 0, 0, 0);
                    sb1 = __builtin_amdgcn_mfma_f32_16x16x32_bf16(kf1, qf[cc], sb1, 0, 0, 0);
                }
            }
            __builtin_amdgcn_s_setprio(0);

            // ---- phase 2: softmax both (batched exp2 on trans pipe) ----
            bf16x8 pfA, pfB;
            {
                const bool needmask = (k0a + 31) > qw0;
                float pp[8];
#pragma unroll
                for (int i = 0; i < 4; ++i) {
                    float v0 = sa0[i], v1 = sa1[i];
                    if (needmask) {
                        if (k0a + 4 * g + i > q_)      v0 = -INFINITY;
                        if (k0a + 16 + 4 * g + i > q_) v1 = -INFINITY;
                    }
                    pp[i]     = EXP2F(v0 - MFIX);
                    pp[4 + i] = EXP2F(v1 - MFIX);
                }
                lsum += ((pp[0] + pp[1]) + (pp[2] + pp[3]))
                      + ((pp[4] + pp[5]) + (pp[6] + pp[7]));
                u32x4 pu = { pk2(pp[0], pp[1]), pk2(pp[2], pp[3]),
                             pk2(pp[4], pp[5]), pk2(pp[6], pp[7]) };
                pfA = __builtin_bit_cast(bf16x8, pu);
            }
            if (do1) {
                const bool needmask = (k0b + 31) > qw0;
                float pp[8];
#pragma unroll
                for (int i = 0; i < 4; ++i) {
                    float v0 = sb0[i], v1 = sb1[i];
                    if (needmask) {
                        if (k0b + 4 * g + i > q_)      v0 = -INFINITY;
                        if (k0b + 16 + 4 * g + i > q_) v1 = -INFINITY;
                    }
                    pp[i]     = EXP2F(v0 - MFIX);
                    pp[4 + i] = EXP2F(v1 - MFIX);
                }
                lsum += ((pp[0] + pp[1]) + (pp[2] + pp[3]))
                      + ((pp[4] + pp[5]) + (pp[6] + pp[7]));
                u32x4 pu = { pk2(pp[0], pp[1]), pk2(pp[2], pp[3]),
                             pk2(pp[4], pp[5]), pk2(pp[6], pp[7]) };
                pfB = __builtin_bit_cast(bf16x8, pu);
            }

            // ---- phase 3: PV both (16 independent MFMA across db) ----
            __builtin_amdgcn_s_setprio(1);
#pragma unroll
            for (int db = 0; db < 8; ++db) {
                bf16x8 vf = *(const bf16x8*)(vbase + (db * 16 + lo) * 128 + ((g * 16) ^ sw));
                o_[db] = __builtin_amdgcn_mfma_f32_16x16x32_bf16(pfA, vf, o_[db], 0, 0, 0);
            }
            if (do1) {
#pragma unroll
                for (int db = 0; db < 8; ++db) {
                    bf16x8 vf = *(const bf16x8*)(vbase + (db * 16 + lo) * 128 + ((64 + g * 16) ^ sw));
                    o_[db] = __builtin_amdgcn_mfma_f32_16x16x32_bf16(pfB, vf, o_[db], 0, 0, 0);
                }
            }
            __builtin_amdgcn_s_setprio(0);
        }
    }

    // ---- epilogue: row-sums live at lanes {lo, lo+16, lo+32, lo+48} ----
    float rs = lsum;
    rs += __shfl_xor(rs, 16);
    rs += __shfl_xor(rs, 32);          // lane x holds rowsum(q = qw0 + (x&15))
#pragma unroll
    for (int i = 0; i < 4; ++i) {
        const float inv = 1.0f / __shfl(rs, 4 * g + i);
        float* op = O + ((size_t)(b * SEQ_ + qw0 + 4 * g + i)) * (H_ * DV_) + h * DV_ + lo;
#pragma unroll
        for (int db = 0; db < 8; ++db) op[db * 16] = o_[db][i] * inv;
    }
}

extern "C" void kernel_launch(void* const* d_in, const int* in_sizes, int n_in,
                              void* d_out, int out_size, void* d_ws, size_t ws_size,
                              hipStream_t stream) {
    const float* Q = (const float*)d_in[0];
    const float* K = (const float*)d_in[1];
    const float* V = (const float*)d_in[2];
    float* Out = (float*)d_out;
    unsigned short* Kb = (unsigned short*)d_ws;                       // 8.39 MB
    unsigned short* Vt = (unsigned short*)((char*)d_ws + VOFF);       // 8.39 MB
    prep_kv<<<dim3(4096), dim3(256), 0, stream>>>(K, V, Kb, Vt);
    attn_fwd<<<dim3(1024), dim3(512), 0, stream>>>(Q, Kb, Out);
}

// Round 29
// 69.206 us; speedup vs baseline: 1.0007x; 1.0007x over previous
//
#include <hip/hip_runtime.h>
#include <hip/hip_bf16.h>

#define H_   32
#define KVH_ 8
#define D_   128
#define DV_  128
#define SEQ_ 1024
#define QKD  (H_*D_)
#define KVD  (KVH_*D_)
#define CS_  (0.08838834764831845f * 1.4426950408889634f)  // SCALE*log2(e)
#define MFIX 8.0f   // fixed softmax max (log2 units)
#define VOFF 8388608  // Vt = Kb + 8 MB in d_ws

typedef __attribute__((ext_vector_type(8))) short bf16x8;
typedef __attribute__((ext_vector_type(8))) unsigned short u16x8;
typedef __attribute__((ext_vector_type(4))) float f32x4;
typedef __attribute__((ext_vector_type(4))) unsigned int u32x4;

typedef const __attribute__((address_space(1))) void* gp_t;
typedef __attribute__((address_space(3))) void* lp_t;

#if __has_builtin(__builtin_amdgcn_exp2f)
#define EXP2F(x) __builtin_amdgcn_exp2f(x)
#else
#define EXP2F(x) exp2f(x)
#endif

static __device__ __forceinline__ unsigned short f2b(float x) {
    __hip_bfloat16 b = __float2bfloat16(x);
    return __builtin_bit_cast(unsigned short, b);
}
static __device__ __forceinline__ unsigned pk2(float a, float b) {
    return (unsigned)f2b(a) | ((unsigned)f2b(b) << 16);
}

// ---------- fused pre-pass ----------
// blocks [0,2048): K f32 [T][KVH*128] -> bf16 [bh][s][128]
// blocks [2048,4096): V f32 -> bf16 transposed + slot-permuted [bh][dv][slot]
//   slot c (within 32-group): k_local = 4*((c>>3)&3) + (c&3) + 16*((c>>2)&1)
__global__ __launch_bounds__(256)
void prep_kv(const float* __restrict__ K, const float* __restrict__ V,
             unsigned short* __restrict__ Kb, unsigned short* __restrict__ Vt) {
    if (blockIdx.x < 2048) {
        const int gt = blockIdx.x * 256 + threadIdx.x;
        const int q  = gt & 15;
        const int r  = gt >> 4;
        const int s  = r & 1023;
        const int bh = r >> 10;
        const int b = bh >> 3, kvh = bh & 7;
        const float* src = K + ((size_t)(b * SEQ_ + s)) * KVD + kvh * D_ + q * 8;
        float4 a = *(const float4*)src;
        float4 c = *(const float4*)(src + 4);
        u32x4 o = { pk2(a.x, a.y), pk2(a.z, a.w), pk2(c.x, c.y), pk2(c.z, c.w) };
        *(u32x4*)(Kb + (size_t)r * 128 + q * 8) = o;
    } else {
        const int gt = (blockIdx.x - 2048) * 256 + threadIdx.x;
        const int dv = gt & 127;
        const int uc = (gt >> 7) & 127;
        const int bh = gt >> 14;
        const int b = bh >> 3, kvh = bh & 7;
        const int C  = uc * 8;
        const int t  = C >> 5;
        const float* src = V + ((size_t)(b * SEQ_)) * KVD + kvh * DV_ + dv;
        unsigned short e[8];
#pragma unroll
        for (int i = 0; i < 8; ++i) {
            const int c = (C & 31) + i;
            const int kl = 4 * ((c >> 3) & 3) + (c & 3) + 16 * ((c >> 2) & 1);
            const int s = (t << 5) + kl;
            e[i] = f2b(src[(size_t)s * KVD]);
        }
        u16x8 o = { e[0], e[1], e[2], e[3], e[4], e[5], e[6], e[7] };
        *(u16x8*)(Vt + ((size_t)bh * 128 + dv) * SEQ_ + C) = o;
    }
}

// ---------- attention: 8 waves, QBLK=128, KVBLK=64, phase-batched sub-iters ----------
// CHAMPION (R27, 67.9us): two 32k sub-iterations PHASE-BATCHED per chunk
// (QK0+QK1 -> softmax0+softmax1 -> PV0+PV1) -> double the independent work at
// every stall point. No setprio (measured neutral-negative both on serial R26
// and phase-batched R28 bodies). Grid 1024 unpaired, LPT (qt = 7-rank) +
// kvh-keyed XCD locking; swapped-QK in-register P; fixed-m softmax; dbuf LDS
// staged via pre-swizzled-source global_load_lds.
// KS tile: [64 k][128 d] bf16, 256B rows, slot-swizzle ^(row&7) (read XOR (lo&7)<<4)
// VT tile: [128 dv][64 slot] bf16, 128B rows, slot-swizzle ^(dv&7) (read XOR (lo&7)<<4)
__global__ __launch_bounds__(512)
void attn_fwd(const float* __restrict__ Q,
              const unsigned short* __restrict__ Kb,
              float* __restrict__ O) {
    __shared__ __align__(16) unsigned short KS[2][64 * 128];   // 16 KB each
    __shared__ __align__(16) unsigned short VT[2][128 * 64];   // 16 KB each

    const int raw = (int)blockIdx.x;
    const int qt  = 7 - (raw >> 7);        // LPT: longest first (8 q-tiles of 128 rows)
    const int low = raw & 127;
    const int kvh = low & 7;               // blockIdx%8 -> XCD-locked kvh
    const int hq  = (low >> 3) & 3;
    const int b   = low >> 5;
    const int h   = kvh * 4 + hq;
    const int bh  = b * 8 + kvh;

    const int tid = threadIdx.x;
    const int w   = tid >> 6;              // wave 0..7
    const int l   = tid & 63;
    const int lo  = l & 15;
    const int g   = l >> 4;

    // staging source offsets (pre-swizzled), thread stages 2 K + 2 V 16B units
    const int kr0 = tid >> 4, ks0 = tid & 15;
    const int kr1 = kr0 + 32;
    const int offk0 = kr0 * 256 + (((ks0 & 8) | ((ks0 & 7) ^ (kr0 & 7))) << 4);
    const int offk1 = kr1 * 256 + (((ks0 & 8) | ((ks0 & 7) ^ (kr1 & 7))) << 4);
    const int dv0 = tid >> 3, vi = tid & 7;
    const int offv0 = VOFF + dv0 * 2048 + ((vi ^ (dv0 & 7)) << 4);
    const int offv1 = VOFF + (dv0 + 64) * 2048 + ((vi ^ (dv0 & 7)) << 4);

    const char* base = (const char*)Kb + (size_t)bh * 262144;  // 1024*128*2

    auto issue = [&](int t, int dsel) {
        char* ksd = (char*)KS[dsel] + w * 1024;
        char* vsd = (char*)VT[dsel] + w * 1024;
        const int ko = t * 16384;   // 64 rows * 256B per chunk
        const int vo = t * 128;     // 64 slots * 2B per chunk within each dv row
        __builtin_amdgcn_global_load_lds((gp_t)(base + (size_t)(offk0 + ko)), (lp_t)ksd,          16, 0, 0);
        __builtin_amdgcn_global_load_lds((gp_t)(base + (size_t)(offk1 + ko)), (lp_t)(ksd + 8192), 16, 0, 0);
        __builtin_amdgcn_global_load_lds((gp_t)(base + (size_t)(offv0 + vo)), (lp_t)vsd,          16, 0, 0);
        __builtin_amdgcn_global_load_lds((gp_t)(base + (size_t)(offv1 + vo)), (lp_t)(vsd + 8192), 16, 0, 0);
    };

    const int ntiles = 2 * qt + 2;         // 64k chunks: cover k <= qt*128+127
    const int qw0    = qt * 128 + w * 16;
    const int jmaxw  = (qw0 + 15) >> 6;    // last chunk this wave needs

    // Q fragments pre-scaled by SCALE*log2(e): row = lo, d = 32c + 8g + e
    const float* Qb = Q + ((size_t)(b * SEQ_ + qw0 + lo)) * QKD + h * D_;
    bf16x8 qf[4];
#pragma unroll
    for (int cc = 0; cc < 4; ++cc) {
        const float* qp = Qb + cc * 32 + g * 8;
        float4 x0 = *(const float4*)(qp);
        float4 x1 = *(const float4*)(qp + 4);
        bf16x8 f;
        f[0] = f2b(x0.x * CS_); f[1] = f2b(x0.y * CS_);
        f[2] = f2b(x0.z * CS_); f[3] = f2b(x0.w * CS_);
        f[4] = f2b(x1.x * CS_); f[5] = f2b(x1.y * CS_);
        f[6] = f2b(x1.z * CS_); f[7] = f2b(x1.w * CS_);
        qf[cc] = f;
    }

    float lsum = 0.f;
    f32x4 o_[8];
#pragma unroll
    for (int db = 0; db < 8; ++db) o_[db] = (f32x4){0.f, 0.f, 0.f, 0.f};

    issue(0, 0);

#pragma unroll 1
    for (int j = 0; j < ntiles; ++j) {
        __syncthreads();                       // chunk j landed; buf[(j+1)&1] free
        if (j + 1 < ntiles) issue(j + 1, (j + 1) & 1);
        if (j <= jmaxw) {
            const int d = j & 1;
            const char* kbase = (const char*)KS[d];
            const char* vbase = (const char*)VT[d];
            const int sw = (lo & 7) << 4;
            const int q_ = qw0 + lo;

            const int k0a = j * 64;
            const int k0b = j * 64 + 32;
            const bool do1 = (k0b <= qw0 + 15);    // wave-uniform

            // ---- phase 1: QK for both sub-tiles (up to 16 back-to-back MFMA) ----
            f32x4 sa0 = (f32x4){0.f, 0.f, 0.f, 0.f};
            f32x4 sa1 = (f32x4){0.f, 0.f, 0.f, 0.f};
            f32x4 sb0 = (f32x4){0.f, 0.f, 0.f, 0.f};
            f32x4 sb1 = (f32x4){0.f, 0.f, 0.f, 0.f};
#pragma unroll
            for (int cc = 0; cc < 4; ++cc) {
                bf16x8 kf0 = *(const bf16x8*)(kbase + (((lo) * 256 + cc * 64 + g * 16) ^ sw));
                bf16x8 kf1 = *(const bf16x8*)(kbase + (((16 + lo) * 256 + cc * 64 + g * 16) ^ sw));
                sa0 = __builtin_amdgcn_mfma_f32_16x16x32_bf16(kf0, qf[cc], sa0, 0, 0, 0);
                sa1 = __builtin_amdgcn_mfma_f32_16x16x32_bf16(kf1, qf[cc], sa1, 0, 0, 0);
            }
            if (do1) {
#pragma unroll
                for (int cc = 0; cc < 4; ++cc) {
                    bf16x8 kf0 = *(const bf16x8*)(kbase + (((32 + lo) * 256 + cc * 64 + g * 16) ^ sw));
                    bf16x8 kf1 = *(const bf16x8*)(kbase + (((48 + lo) * 256 + cc * 64 + g * 16) ^ sw));
                    sb0 = __builtin_amdgcn_mfma_f32_16x16x32_bf16(kf0, qf[cc], sb0, 0, 0, 0);
                    sb1 = __builtin_amdgcn_mfma_f32_16x16x32_bf16(kf1, qf[cc], sb1, 0, 0, 0);
                }
            }

            // ---- phase 2: softmax both (batched exp2 on trans pipe) ----
            bf16x8 pfA, pfB;
            {
                const bool needmask = (k0a + 31) > qw0;
                float pp[8];
#pragma unroll
                for (int i = 0; i < 4; ++i) {
                    float v0 = sa0[i], v1 = sa1[i];
                    if (needmask) {
                        if (k0a + 4 * g + i > q_)      v0 = -INFINITY;
                        if (k0a + 16 + 4 * g + i > q_) v1 = -INFINITY;
                    }
                    pp[i]     = EXP2F(v0 - MFIX);
                    pp[4 + i] = EXP2F(v1 - MFIX);
                }
                lsum += ((pp[0] + pp[1]) + (pp[2] + pp[3]))
                      + ((pp[4] + pp[5]) + (pp[6] + pp[7]));
                u32x4 pu = { pk2(pp[0], pp[1]), pk2(pp[2], pp[3]),
                             pk2(pp[4], pp[5]), pk2(pp[6], pp[7]) };
                pfA = __builtin_bit_cast(bf16x8, pu);
            }
            if (do1) {
                const bool needmask = (k0b + 31) > qw0;
                float pp[8];
#pragma unroll
                for (int i = 0; i < 4; ++i) {
                    float v0 = sb0[i], v1 = sb1[i];
                    if (needmask) {
                        if (k0b + 4 * g + i > q_)      v0 = -INFINITY;
                        if (k0b + 16 + 4 * g + i > q_) v1 = -INFINITY;
                    }
                    pp[i]     = EXP2F(v0 - MFIX);
                    pp[4 + i] = EXP2F(v1 - MFIX);
                }
                lsum += ((pp[0] + pp[1]) + (pp[2] + pp[3]))
                      + ((pp[4] + pp[5]) + (pp[6] + pp[7]));
                u32x4 pu = { pk2(pp[0], pp[1]), pk2(pp[2], pp[3]),
                             pk2(pp[4], pp[5]), pk2(pp[6], pp[7]) };
                pfB = __builtin_bit_cast(bf16x8, pu);
            }

            // ---- phase 3: PV both (16 independent MFMA across db) ----
#pragma unroll
            for (int db = 0; db < 8; ++db) {
                bf16x8 vf = *(const bf16x8*)(vbase + (db * 16 + lo) * 128 + ((g * 16) ^ sw));
                o_[db] = __builtin_amdgcn_mfma_f32_16x16x32_bf16(pfA, vf, o_[db], 0, 0, 0);
            }
            if (do1) {
#pragma unroll
                for (int db = 0; db < 8; ++db) {
                    bf16x8 vf = *(const bf16x8*)(vbase + (db * 16 + lo) * 128 + ((64 + g * 16) ^ sw));
                    o_[db] = __builtin_amdgcn_mfma_f32_16x16x32_bf16(pfB, vf, o_[db], 0, 0, 0);
                }
            }
        }
    }

    // ---- epilogue: row-sums live at lanes {lo, lo+16, lo+32, lo+48} ----
    float rs = lsum;
    rs += __shfl_xor(rs, 16);
    rs += __shfl_xor(rs, 32);          // lane x holds rowsum(q = qw0 + (x&15))
#pragma unroll
    for (int i = 0; i < 4; ++i) {
        const float inv = 1.0f / __shfl(rs, 4 * g + i);
        float* op = O + ((size_t)(b * SEQ_ + qw0 + 4 * g + i)) * (H_ * DV_) + h * DV_ + lo;
#pragma unroll
        for (int db = 0; db < 8; ++db) op[db * 16] = o_[db][i] * inv;
    }
}

extern "C" void kernel_launch(void* const* d_in, const int* in_sizes, int n_in,
                              void* d_out, int out_size, void* d_ws, size_t ws_size,
                              hipStream_t stream) {
    const float* Q = (const float*)d_in[0];
    const float* K = (const float*)d_in[1];
    const float* V = (const float*)d_in[2];
    float* Out = (float*)d_out;
    unsigned short* Kb = (unsigned short*)d_ws;                       // 8.39 MB
    unsigned short* Vt = (unsigned short*)((char*)d_ws + VOFF);       // 8.39 MB
    prep_kv<<<dim3(4096), dim3(256), 0, stream>>>(K, V, Kb, Vt);
    attn_fwd<<<dim3(1024), dim3(512), 0, stream>>>(Q, Kb, Out);
}